// Round 2
// 142.881 us; speedup vs baseline: 1.0208x; 1.0208x over previous
//
#include <hip/hip_runtime.h>
#include <math.h>

#define NPOS 4096
#define DCH  512
#define HD   32
#define NH   16
#define KW   9
#define DIL  3
#define PAD  12
#define TILE   128
#define NTILES (NPOS / TILE)       // 32
#define SPANT  (TILE + 2*PAD)      // 152 tokens staged per tile
#define ROWF4  (SPANT / 4)         // 38 real float4 per channel row
#define SLDS   156                 // LDS row stride in floats (152 + 4 pad = 39 f4)
#define ROWC   (SLDS / 4)          // 39 16B chunks per row (incl pad chunk)
#define NCHK   (HD * ROWC)         // 1248 chunks per buffer (k or v)
#define CSPL   8                   // channel-split lanes per token-group
#define CPT    (HD / CSPL)         // 4 channels per thread
#define TPT    4                   // tokens per thread
#define WSPAN  28                  // 4 tokens x 9 taps span 28 tokens

// Direct global->LDS (16B). LDS dest is wave-uniform base + lane*16; we only
// call it with per-lane ptrs that are linear in lane with prefix-active guards.
__device__ __forceinline__ void gload16(const float* g, float* l) {
    __builtin_amdgcn_global_load_lds(
        (const __attribute__((address_space(1))) void*)g,
        (__attribute__((address_space(3))) void*)l,
        16, 0, 0);
}

// Butterfly sum over 8 consecutive lanes (aligned groups) — pure VALU via DPP.
// Stages: xor1 = quad_perm(1,0,3,2)=0xB1, xor2 = quad_perm(2,3,0,1)=0x4E,
// cross-quad within 8 = row_half_mirror (0x141, lane i <-> 7-i in each 8-group).
__device__ __forceinline__ float dpp_sum8(float x) {
    int t;
    t = __builtin_amdgcn_update_dpp(0, __float_as_int(x), 0xB1, 0xF, 0xF, true);
    x += __int_as_float(t);
    t = __builtin_amdgcn_update_dpp(0, __float_as_int(x), 0x4E, 0xF, 0xF, true);
    x += __int_as_float(t);
    t = __builtin_amdgcn_update_dpp(0, __float_as_int(x), 0x141, 0xF, 0xF, true);
    x += __int_as_float(t);
    return x;
}

__global__ __launch_bounds__(256) void dilate_attn_kernel(
    const float* __restrict__ q,
    const float* __restrict__ k,
    const float* __restrict__ v,
    float* __restrict__ out)
{
    // Single contiguous buffer: k rows then v rows (chunk-linear for gload16).
    __shared__ float kv[2 * HD * SLDS];
    float* const ks = kv;
    float* const vs = kv + HD * SLDS;

    const int bh   = blockIdx.x >> 5;            // 0..63  (b*16+h)
    const int tile = blockIdx.x & (NTILES - 1);  // 0..31
    const int n0t  = tile * TILE;                // first token of tile
    const int ws   = n0t - PAD;                  // staged span start (may be <0)

    const size_t cb = (size_t)bh * HD * NPOS;
    const float* kg = k + cb;
    const float* vg = v + cb;
    const float* qg = q + cb;

    // easy <=> staged span fully interior <=> ALL taps of ALL tile tokens valid
    const bool easy = (ws >= 0) && (ws + SPANT <= NPOS);

    // ---------------- Stage k,v spans into LDS ------------------------------
    if (easy) {
        // global_load_lds_dwordx4, chunk-linear. Pad chunk (c4==38) reads
        // floats ws+152..ws+155: in-bounds for every easy tile (max ws=3828).
#pragma unroll
        for (int it = 0; it < 5; ++it) {
            int c = it * 256 + (int)threadIdx.x;
            if (c < NCHK) {
                int row = c / ROWC;
                int c4  = c - row * ROWC;
                gload16(kg + (size_t)row * NPOS + (ws + c4 * 4),
                        &kv[(size_t)c * 4]);
            }
        }
#pragma unroll
        for (int it = 0; it < 5; ++it) {
            int c = it * 256 + (int)threadIdx.x;
            if (c < NCHK) {
                int row = c / ROWC;
                int c4  = c - row * ROWC;
                gload16(vg + (size_t)row * NPOS + (ws + c4 * 4),
                        &kv[(size_t)(NCHK + c) * 4]);
            }
        }
    } else {                                      // edge tiles (2 of 32): clamped
        for (int p = threadIdx.x; p < HD * ROWF4; p += 256) {
            int row = p / ROWF4;
            int c4  = p - row * ROWF4;
            int g0  = ws + c4 * 4;
            const float* kr = kg + (size_t)row * NPOS;
            const float* vr = vg + (size_t)row * NPOS;
            float4 kk, vv;
            if (g0 >= 0 && g0 + 4 <= NPOS) {
                kk = *(const float4*)(kr + g0);
                vv = *(const float4*)(vr + g0);
            } else {
                int i0 = min(max(g0 + 0, 0), NPOS - 1);
                int i1 = min(max(g0 + 1, 0), NPOS - 1);
                int i2 = min(max(g0 + 2, 0), NPOS - 1);
                int i3 = min(max(g0 + 3, 0), NPOS - 1);
                kk = make_float4(kr[i0], kr[i1], kr[i2], kr[i3]);
                vv = make_float4(vr[i0], vr[i1], vr[i2], vr[i3]);
            }
            *(float4*)&ks[row * SLDS + c4 * 4] = kk;
            *(float4*)&vs[row * SLDS + c4 * 4] = vv;
        }
    }

    // ---------------- q loads (global, coalesced; overlap staging) ---------
    const int cs = threadIdx.x & (CSPL - 1);     // lane&7: channel octet slot
    const int lg = threadIdx.x >> 3;             // 0..31: token group in tile
    const int n0 = n0t + lg * TPT;               // first token this thread owns

    float4 qv[CPT];
#pragma unroll
    for (int i = 0; i < CPT; ++i) {
        int ch = cs * CPT + i;
        qv[i] = *(const float4*)(qg + (size_t)ch * NPOS + n0);
    }

    __syncthreads();

    // ---------------- Pass 1: partial scores from LDS k ---------------------
    float s[TPT][KW];
#pragma unroll
    for (int t = 0; t < TPT; ++t)
#pragma unroll
        for (int j = 0; j < KW; ++j) s[t][j] = 0.0f;

#pragma unroll
    for (int i = 0; i < CPT; ++i) {
        int row = cs * CPT + i;
        const float4* wp = (const float4*)&ks[row * SLDS + lg * TPT];
        float w[WSPAN];
#pragma unroll
        for (int u = 0; u < WSPAN / 4; ++u) {
            float4 x = wp[u];
            w[4*u] = x.x; w[4*u+1] = x.y; w[4*u+2] = x.z; w[4*u+3] = x.w;
        }
        float qt[TPT] = {qv[i].x, qv[i].y, qv[i].z, qv[i].w};
#pragma unroll
        for (int t = 0; t < TPT; ++t)
#pragma unroll
            for (int j = 0; j < KW; ++j)
                s[t][j] = fmaf(qt[t], w[t + 3*j], s[t][j]);
    }

    // Reduce partial scores across the 8 channel-split lanes (DPP, no DS ops)
#pragma unroll
    for (int t = 0; t < TPT; ++t)
#pragma unroll
        for (int j = 0; j < KW; ++j)
            s[t][j] = dpp_sum8(s[t][j]);

    // ---------------- Softmax per token -------------------------------------
    const float scale = 0.17677669529663687f;    // 32^-0.5
    if (easy) {
        // all taps valid: no masks at all
#pragma unroll
        for (int t = 0; t < TPT; ++t) {
            float m = -INFINITY;
#pragma unroll
            for (int j = 0; j < KW; ++j) {
                float x = s[t][j] * scale;
                s[t][j] = x;
                m = fmaxf(m, x);
            }
            float sum = 0.0f;
#pragma unroll
            for (int j = 0; j < KW; ++j) {
                float e = __expf(s[t][j] - m);
                s[t][j] = e;
                sum += e;
            }
            float inv = 1.0f / sum;
#pragma unroll
            for (int j = 0; j < KW; ++j) s[t][j] *= inv;
        }
    } else {
        // edge tiles: invalid taps have logit exactly 0, prob zeroed at the end
#pragma unroll
        for (int t = 0; t < TPT; ++t) {
            float vm[KW];
            float m = -INFINITY;
#pragma unroll
            for (int j = 0; j < KW; ++j) {
                vm[j] = ((unsigned)(n0 + t + 3*j - PAD) < NPOS) ? 1.0f : 0.0f;
                float x = s[t][j] * scale * vm[j];
                s[t][j] = x;
                m = fmaxf(m, x);
            }
            float sum = 0.0f;
#pragma unroll
            for (int j = 0; j < KW; ++j) {
                float e = __expf(s[t][j] - m);
                s[t][j] = e;
                sum += e;
            }
            float inv = 1.0f / sum;
#pragma unroll
            for (int j = 0; j < KW; ++j)
                s[t][j] *= inv * vm[j];          // s now holds probabilities
        }
    }

    // ---------------- Pass 2: output from LDS v ------------------------------
    float o[TPT][CPT];
#pragma unroll
    for (int t = 0; t < TPT; ++t)
#pragma unroll
        for (int i = 0; i < CPT; ++i) o[t][i] = 0.0f;

#pragma unroll
    for (int i = 0; i < CPT; ++i) {
        int row = cs * CPT + i;
        const float4* wp = (const float4*)&vs[row * SLDS + lg * TPT];
        float w[WSPAN];
#pragma unroll
        for (int u = 0; u < WSPAN / 4; ++u) {
            float4 x = wp[u];
            w[4*u] = x.x; w[4*u+1] = x.y; w[4*u+2] = x.z; w[4*u+3] = x.w;
        }
#pragma unroll
        for (int t = 0; t < TPT; ++t)
#pragma unroll
            for (int j = 0; j < KW; ++j)
                o[t][i] = fmaf(s[t][j], w[t + 3*j], o[t][i]);
    }

    // ---------------- Store: one float4 per token (octet -> 128B/token) ----
    const int b  = bh >> 4;
    const int hh = bh & (NH - 1);
#pragma unroll
    for (int t = 0; t < TPT; ++t) {
        float* op = out + ((size_t)(b * NPOS + n0 + t)) * DCH + hh * HD + cs * CPT;
        *(float4*)op = make_float4(o[t][0], o[t][1], o[t][2], o[t][3]);
    }
}

extern "C" void kernel_launch(void* const* d_in, const int* in_sizes, int n_in,
                              void* d_out, int out_size, void* d_ws, size_t ws_size,
                              hipStream_t stream) {
    const float* q = (const float*)d_in[0];
    const float* k = (const float*)d_in[1];
    const float* v = (const float*)d_in[2];
    float* out = (float*)d_out;

    const int grid = 4 * NH * NTILES;   // 64 bh * 32 tiles = 2048 blocks
    hipLaunchKernelGGL(dilate_attn_kernel, dim3(grid), dim3(256), 0, stream,
                       q, k, v, out);
}

// Round 3
// 141.164 us; speedup vs baseline: 1.0332x; 1.0122x over previous
//
#include <hip/hip_runtime.h>
#include <math.h>

#define NPOS 4096
#define DCH  512
#define HD   32
#define NH   16
#define KW   9
#define DIL  3
#define PAD  12
#define TILE   128
#define NTILES (NPOS / TILE)       // 32
#define SPANT  (TILE + 2*PAD)      // 152 tokens staged per tile
#define ROWF4  (SPANT / 4)         // 38 real float4 per channel row
#define SLDS   156                 // LDS row stride in floats (152 + 4 pad = 39 f4)
#define ROWC   (SLDS / 4)          // 39 16B chunks per row (incl pad chunk)
#define NCHK   (HD * ROWC)         // 1248 chunks per buffer (k or v)
#define CSPL   8                   // channel-split lanes per token-group
#define CPT    (HD / CSPL)         // 4 channels per thread
#define TPT    4                   // tokens per thread
#define WSPAN  28                  // 4 tokens x 9 taps span 28 tokens

// Direct global->LDS (16B).
__device__ __forceinline__ void gload16(const float* g, float* l) {
    __builtin_amdgcn_global_load_lds(
        (const __attribute__((address_space(1))) void*)g,
        (__attribute__((address_space(3))) void*)l,
        16, 0, 0);
}

// Butterfly sum over 8 consecutive lanes — pure VALU via DPP.
__device__ __forceinline__ float dpp_sum8(float x) {
    int t;
    t = __builtin_amdgcn_update_dpp(0, __float_as_int(x), 0xB1, 0xF, 0xF, true);
    x += __int_as_float(t);
    t = __builtin_amdgcn_update_dpp(0, __float_as_int(x), 0x4E, 0xF, 0xF, true);
    x += __int_as_float(t);
    t = __builtin_amdgcn_update_dpp(0, __float_as_int(x), 0x141, 0xF, 0xF, true);
    x += __int_as_float(t);
    return x;
}

// Load 28-float window (7 x ds_read_b128) from an LDS row.
__device__ __forceinline__ void load_w(const float* base, float* w) {
    const float4* wp = (const float4*)base;
#pragma unroll
    for (int u = 0; u < WSPAN / 4; ++u) {
        float4 x = wp[u];
        w[4*u] = x.x; w[4*u+1] = x.y; w[4*u+2] = x.z; w[4*u+3] = x.w;
    }
}

// QK^T partials + 8-lane reduce.
__device__ __forceinline__ void qk_pass(const float* ksb, int cs, int lg,
                                        const float4* qv, float s[TPT][KW]) {
#pragma unroll
    for (int t = 0; t < TPT; ++t)
#pragma unroll
        for (int j = 0; j < KW; ++j) s[t][j] = 0.0f;
#pragma unroll
    for (int i = 0; i < CPT; ++i) {
        int row = cs * CPT + i;
        float w[WSPAN];
        load_w(ksb + row * SLDS + lg * TPT, w);
        float qt[TPT] = {qv[i].x, qv[i].y, qv[i].z, qv[i].w};
#pragma unroll
        for (int t = 0; t < TPT; ++t)
#pragma unroll
            for (int j = 0; j < KW; ++j)
                s[t][j] = fmaf(qt[t], w[t + 3*j], s[t][j]);
    }
#pragma unroll
    for (int t = 0; t < TPT; ++t)
#pragma unroll
        for (int j = 0; j < KW; ++j)
            s[t][j] = dpp_sum8(s[t][j]);
}

// P·V accumulate.
__device__ __forceinline__ void pv_pass(const float* vsb, int cs, int lg,
                                        const float s[TPT][KW], float o[TPT][CPT]) {
#pragma unroll
    for (int t = 0; t < TPT; ++t)
#pragma unroll
        for (int i = 0; i < CPT; ++i) o[t][i] = 0.0f;
#pragma unroll
    for (int i = 0; i < CPT; ++i) {
        int row = cs * CPT + i;
        float w[WSPAN];
        load_w(vsb + row * SLDS + lg * TPT, w);
#pragma unroll
        for (int t = 0; t < TPT; ++t)
#pragma unroll
            for (int j = 0; j < KW; ++j)
                o[t][i] = fmaf(s[t][j], w[t + 3*j], o[t][i]);
    }
}

__global__ __launch_bounds__(256) void dilate_attn_kernel(
    const float* __restrict__ q,
    const float* __restrict__ k,
    const float* __restrict__ v,
    float* __restrict__ out)
{
    // Single contiguous buffer: k rows then v rows (chunk-linear for gload16).
    __shared__ float kv[2 * HD * SLDS];
    float* const ks = kv;
    float* const vs = kv + HD * SLDS;

    const int bh   = blockIdx.x >> 5;            // 0..63  (b*16+h)
    const int tile = blockIdx.x & (NTILES - 1);  // 0..31
    const int n0t  = tile * TILE;                // first token of tile
    const int ws   = n0t - PAD;                  // staged span start (may be <0)

    const size_t cb = (size_t)bh * HD * NPOS;
    const float* kg = k + cb;
    const float* vg = v + cb;
    const float* qg = q + cb;

    const int cs = threadIdx.x & (CSPL - 1);     // lane&7: channel octet slot
    const int lg = threadIdx.x >> 3;             // 0..31: token group in tile
    const int n0 = n0t + lg * TPT;               // first token this thread owns

    // easy <=> staged span fully interior <=> ALL taps of ALL tile tokens valid
    const bool easy = (ws >= 0) && (ws + SPANT <= NPOS);
    const float scale = 0.17677669529663687f;    // 32^-0.5

    float4 qv[CPT];
    float  s[TPT][KW];
    float  o[TPT][CPT];

    if (easy) {
        // ---- issue order matters for counted vmcnt: q (oldest), K, V ------
        // q: 4 global_load_dwordx4 per wave (to VGPR)
#pragma unroll
        for (int i = 0; i < CPT; ++i)
            qv[i] = *(const float4*)(qg + (size_t)(cs * CPT + i) * NPOS + n0);
        asm volatile("" ::: "memory");           // pin q before K
        // K: 5 global_load_lds_dwordx4 per wave (all waves issue all 5)
#pragma unroll
        for (int it = 0; it < 5; ++it) {
            int c = it * 256 + (int)threadIdx.x;
            if (c < NCHK) {
                int row = c / ROWC;
                int c4  = c - row * ROWC;
                gload16(kg + (size_t)row * NPOS + (ws + c4 * 4), &kv[c * 4]);
            }
        }
        asm volatile("" ::: "memory");           // pin K before V
        // V: 5 global_load_lds_dwordx4 per wave
#pragma unroll
        for (int it = 0; it < 5; ++it) {
            int c = it * 256 + (int)threadIdx.x;
            if (c < NCHK) {
                int row = c / ROWC;
                int c4  = c - row * ROWC;
                gload16(vg + (size_t)row * NPOS + (ws + c4 * 4),
                        &kv[(NCHK + c) * 4]);
            }
        }
        // Wait own q(4)+K(5) retired (in-order vmcnt); V(5) stays in flight.
        asm volatile("s_waitcnt vmcnt(5)" ::: "memory");
        __builtin_amdgcn_s_barrier();            // all waves' K visible
        asm volatile("" ::: "memory");

        // ---- pass 1 + softmax, V staging overlapped underneath -------------
        qk_pass(ks, cs, lg, qv, s);
#pragma unroll
        for (int t = 0; t < TPT; ++t) {
            float m = -INFINITY;
#pragma unroll
            for (int j = 0; j < KW; ++j) {
                float x = s[t][j] * scale;
                s[t][j] = x;
                m = fmaxf(m, x);
            }
            float sum = 0.0f;
#pragma unroll
            for (int j = 0; j < KW; ++j) {
                float e = __expf(s[t][j] - m);
                s[t][j] = e;
                sum += e;
            }
            float inv = 1.0f / sum;
#pragma unroll
            for (int j = 0; j < KW; ++j) s[t][j] *= inv;
        }

        // Own V retired; barrier so ALL waves' V writes are visible.
        asm volatile("s_waitcnt vmcnt(0)" ::: "memory");
        __builtin_amdgcn_s_barrier();
        asm volatile("" ::: "memory");

        pv_pass(vs, cs, lg, s, o);
    } else {
        // ---- edge tiles (2 of 32): clamped scalar staging, full drain ------
        for (int p = threadIdx.x; p < HD * ROWF4; p += 256) {
            int row = p / ROWF4;
            int c4  = p - row * ROWF4;
            int g0  = ws + c4 * 4;
            const float* kr = kg + (size_t)row * NPOS;
            const float* vr = vg + (size_t)row * NPOS;
            float4 kk, vv;
            if (g0 >= 0 && g0 + 4 <= NPOS) {
                kk = *(const float4*)(kr + g0);
                vv = *(const float4*)(vr + g0);
            } else {
                int i0 = min(max(g0 + 0, 0), NPOS - 1);
                int i1 = min(max(g0 + 1, 0), NPOS - 1);
                int i2 = min(max(g0 + 2, 0), NPOS - 1);
                int i3 = min(max(g0 + 3, 0), NPOS - 1);
                kk = make_float4(kr[i0], kr[i1], kr[i2], kr[i3]);
                vv = make_float4(vr[i0], vr[i1], vr[i2], vr[i3]);
            }
            *(float4*)&ks[row * SLDS + c4 * 4] = kk;
            *(float4*)&vs[row * SLDS + c4 * 4] = vv;
        }
#pragma unroll
        for (int i = 0; i < CPT; ++i)
            qv[i] = *(const float4*)(qg + (size_t)(cs * CPT + i) * NPOS + n0);

        __syncthreads();

        qk_pass(ks, cs, lg, qv, s);
        // invalid taps: logit exactly 0, prob zeroed at the end
#pragma unroll
        for (int t = 0; t < TPT; ++t) {
            float vm[KW];
            float m = -INFINITY;
#pragma unroll
            for (int j = 0; j < KW; ++j) {
                vm[j] = ((unsigned)(n0 + t + 3*j - PAD) < NPOS) ? 1.0f : 0.0f;
                float x = s[t][j] * scale * vm[j];
                s[t][j] = x;
                m = fmaxf(m, x);
            }
            float sum = 0.0f;
#pragma unroll
            for (int j = 0; j < KW; ++j) {
                float e = __expf(s[t][j] - m);
                s[t][j] = e;
                sum += e;
            }
            float inv = 1.0f / sum;
#pragma unroll
            for (int j = 0; j < KW; ++j)
                s[t][j] *= inv * vm[j];
        }
        pv_pass(vs, cs, lg, s, o);
    }

    // ---------------- Store: one float4 per token (octet -> 128B/token) ----
    const int b  = bh >> 4;
    const int hh = bh & (NH - 1);
#pragma unroll
    for (int t = 0; t < TPT; ++t) {
        float* op = out + ((size_t)(b * NPOS + n0 + t)) * DCH + hh * HD + cs * CPT;
        *(float4*)op = make_float4(o[t][0], o[t][1], o[t][2], o[t][3]);
    }
}

extern "C" void kernel_launch(void* const* d_in, const int* in_sizes, int n_in,
                              void* d_out, int out_size, void* d_ws, size_t ws_size,
                              hipStream_t stream) {
    const float* q = (const float*)d_in[0];
    const float* k = (const float*)d_in[1];
    const float* v = (const float*)d_in[2];
    float* out = (float*)d_out;

    const int grid = 4 * NH * NTILES;   // 64 bh * 32 tiles = 2048 blocks
    hipLaunchKernelGGL(dilate_attn_kernel, dim3(grid), dim3(256), 0, stream,
                       q, k, v, out);
}